// Round 16
// baseline (143.785 us; speedup 1.0000x reference)
//
#include <hip/hip_runtime.h>
#include <hip/hip_bf16.h>
#include <cstddef>
#include <cstdint>

// Problem constants: B=16, CIN=COUT=64, HID=32, H=W=32, K=5, PAD=2
#define NTOK 1024      // H*W
#define NB   16        // batch
#define NC   64        // channels (CIN == COUT)
#define NHID 32        // attention hidden

// padded conv input: pad[b][kh][36*36 px][64 c] bf16
#define PAD_BSTRIDE 165888   // 2*1296*64
#define PAD_KSTRIDE 82944    // 1296*64
#define PAD_BYTES   5308416  // 16 * PAD_BSTRIDE * 2

typedef __attribute__((ext_vector_type(8))) short short8;   // 8 bf16 = 4 VGPR (MFMA A/B frag)
typedef __attribute__((ext_vector_type(4))) float f32x4;    // MFMA acc frag / native v4f

// round-to-nearest-even f32 -> bf16 (as raw ushort)
__device__ __forceinline__ ushort f2b(float f) {
  uint32_t u = __builtin_bit_cast(uint32_t, f);
  return (ushort)((u + 0x7FFFu + ((u >> 16) & 1u)) >> 16);
}
__device__ __forceinline__ float b2f(ushort u) {
  return __builtin_bit_cast(float, (uint32_t)u << 16);
}
// 8 consecutive f32 -> bf16x8 frag
__device__ __forceinline__ short8 ldw8(const float* __restrict__ p) {
  float4 f0 = *(const float4*)p, f1 = *(const float4*)(p + 4);
  short8 r;
  r[0] = (short)f2b(f0.x); r[1] = (short)f2b(f0.y);
  r[2] = (short)f2b(f0.z); r[3] = (short)f2b(f0.w);
  r[4] = (short)f2b(f1.x); r[5] = (short)f2b(f1.y);
  r[6] = (short)f2b(f1.z); r[7] = (short)f2b(f1.w);
  return r;
}
__device__ __forceinline__ float sigm(float x) { return 1.f / (1.f + __expf(-x)); }
__device__ __forceinline__ float tanh_fast(float x) {
  float e = __expf(2.f * x);
  return 1.f - 2.f / (e + 1.f);   // safe at +/-inf
}
// async global->LDS, 16B/lane: writes l + lane*16 from per-lane g
__device__ __forceinline__ void glds16(const ushort* g, ushort* l) {
  __builtin_amdgcn_global_load_lds(
      (const __attribute__((address_space(1))) unsigned int*)g,
      (__attribute__((address_space(3))) unsigned int*)l, 16, 0, 0);
}

// ---- transpose + convert h f32 [b][64c][1024n] -> padded conv-input interior
__global__ __launch_bounds__(256) void tpose_pad_kernel(
    const float* __restrict__ src, ushort* __restrict__ dst) {
  __shared__ float tile[64][65];
  int t = threadIdx.x;
  int n0 = blockIdx.x * 64, b = blockIdx.y;
  const float* s = src + (size_t)b * NC * NTOK;
#pragma unroll
  for (int r = 0; r < 4; ++r) {
    int c = r * 16 + (t >> 4);
    int nl = (t & 15) * 4;
    float4 v = *(const float4*)(s + (size_t)c * NTOK + n0 + nl);
    tile[c][nl] = v.x; tile[c][nl + 1] = v.y; tile[c][nl + 2] = v.z; tile[c][nl + 3] = v.w;
  }
  __syncthreads();
  int tok = t >> 2, c0 = (t & 3) * 16;
  __attribute__((aligned(16))) ushort tmp[16];
#pragma unroll
  for (int i = 0; i < 16; ++i) tmp[i] = f2b(tile[c0 + i][tok]);
  int gtok = n0 + tok;
  ushort* d = dst + (size_t)b * PAD_BSTRIDE +
              ((gtok >> 5) + 2) * 2304 + ((gtok & 31) + 2) * 64 + c0;
  *(uint4*)(d)     = *(const uint4*)(tmp);
  *(uint4*)(d + 8) = *(const uint4*)(tmp + 8);
}

// ---- fused transpose + q,k,v projection via MFMA (reads f32 channel-major x).
__global__ __launch_bounds__(256) void qkvproj_kernel(
    const float* __restrict__ x, const float* __restrict__ Wq,
    const float* __restrict__ Wk, const float* __restrict__ Wv,
    ushort* __restrict__ qT, ushort* __restrict__ kT, ushort* __restrict__ vb) {
  __shared__ float tile[64][65];
  __shared__ ushort xb[64][72];
  __shared__ ushort sq[64][32], sk[64][32];
  int t = threadIdx.x, wave = t >> 6, lane = t & 63;
  int lo = lane & 15, lg = lane >> 4;
  int n0 = blockIdx.x * 64, b = blockIdx.y;
  const float* s = x + (size_t)b * NC * NTOK;
#pragma unroll
  for (int r = 0; r < 4; ++r) {
    int c = r * 16 + (t >> 4);
    int nl = (t & 15) * 4;
    float4 v = *(const float4*)(s + (size_t)c * NTOK + n0 + nl);
    tile[c][nl] = v.x; tile[c][nl + 1] = v.y; tile[c][nl + 2] = v.z; tile[c][nl + 3] = v.w;
  }
  __syncthreads();
  {
    int tok = t >> 2, c0 = (t & 3) * 16;
    __attribute__((aligned(16))) ushort tmp[16];
#pragma unroll
    for (int i = 0; i < 16; ++i) tmp[i] = f2b(tile[c0 + i][tok]);
    *(uint4*)(&xb[tok][c0])     = *(const uint4*)(tmp);
    *(uint4*)(&xb[tok][c0 + 8]) = *(const uint4*)(tmp + 8);
  }
  __syncthreads();
  const ushort* xrow = &xb[wave * 16 + lo][8 * lg];
  short8 a0 = *(const short8*)(xrow);
  short8 a1 = *(const short8*)(xrow + 32);
  f32x4 aq[2], ak[2];
#pragma unroll
  for (int dg = 0; dg < 2; ++dg) {
    short8 wq0 = ldw8(Wq + (size_t)(dg * 16 + lo) * NC + 8 * lg);
    short8 wq1 = ldw8(Wq + (size_t)(dg * 16 + lo) * NC + 32 + 8 * lg);
    short8 wk0 = ldw8(Wk + (size_t)(dg * 16 + lo) * NC + 8 * lg);
    short8 wk1 = ldw8(Wk + (size_t)(dg * 16 + lo) * NC + 32 + 8 * lg);
    f32x4 z = {0.f, 0.f, 0.f, 0.f};
    aq[dg] = __builtin_amdgcn_mfma_f32_16x16x32_bf16(a0, wq0, z, 0, 0, 0);
    aq[dg] = __builtin_amdgcn_mfma_f32_16x16x32_bf16(a1, wq1, aq[dg], 0, 0, 0);
    ak[dg] = __builtin_amdgcn_mfma_f32_16x16x32_bf16(a0, wk0, z, 0, 0, 0);
    ak[dg] = __builtin_amdgcn_mfma_f32_16x16x32_bf16(a1, wk1, ak[dg], 0, 0, 0);
  }
  f32x4 av[4];
#pragma unroll
  for (int g = 0; g < 4; ++g) {
    short8 wv0 = ldw8(Wv + (size_t)(g * 16 + lo) * NC + 8 * lg);
    short8 wv1 = ldw8(Wv + (size_t)(g * 16 + lo) * NC + 32 + 8 * lg);
    f32x4 z = {0.f, 0.f, 0.f, 0.f};
    av[g] = __builtin_amdgcn_mfma_f32_16x16x32_bf16(wv0, a0, z, 0, 0, 0);
    av[g] = __builtin_amdgcn_mfma_f32_16x16x32_bf16(wv1, a1, av[g], 0, 0, 0);
  }
#pragma unroll
  for (int dg = 0; dg < 2; ++dg)
#pragma unroll
    for (int r = 0; r < 4; ++r) {
      sq[wave * 16 + 4 * lg + r][dg * 16 + lo] = f2b(aq[dg][r]);
      sk[wave * 16 + 4 * lg + r][dg * 16 + lo] = f2b(ak[dg][r]);
    }
  ushort* vbase = vb + (size_t)b * NC * NTOK + n0 + wave * 16 + lo;
#pragma unroll
  for (int g = 0; g < 4; ++g)
#pragma unroll
    for (int r = 0; r < 4; ++r)
      vbase[(size_t)(g * 16 + lg * 4 + r) * NTOK] = f2b(av[g][r]);
  __syncthreads();
  int tok = t >> 2, d0 = (t & 3) * 8;
  size_t base = ((size_t)b * NTOK + n0 + tok) * NHID + d0;
  *(short8*)(qT + base) = *(const short8*)(&sq[tok][d0]);
  *(short8*)(kT + base) = *(const short8*)(&sk[tok][d0]);
}

// ---- FUSED attention: scores (MFMA) -> softmax -> S->bf16 LDS -> coalesced
// NONTEMPORAL atten write (ATTN2) -> PV (MFMA, 2-chain) -> residual epilogue.
#define SP 1048   // S-LDS pitch (ushorts): bank stride 12 -> <=2-way
template <bool ATTN2>
__global__ __launch_bounds__(256) void attn_fused_kernel(
    const ushort* __restrict__ qT, const ushort* __restrict__ kT,
    const ushort* __restrict__ vb, const float* __restrict__ resid,
    float* __restrict__ attnf, float* __restrict__ outf,
    ushort* __restrict__ outb_pad, float scale) {
  __shared__ ushort s_lds[16 * SP];
  __shared__ float wmax[4][16], wsum[4][16];
  int t = threadIdx.x, wave = t >> 6, lane = t & 63;
  int lo = lane & 15, lg = lane >> 4;
  int n0 = blockIdx.x * 16, b = blockIdx.y;
  int m0 = wave * 256;
  short8 a = *(const short8*)(qT + ((size_t)b * NTOK + n0 + lo) * NHID + 8 * lg);
  f32x4 acc[16];
  __builtin_amdgcn_s_setprio(1);
#pragma unroll
  for (int j = 0; j < 16; ++j) {
    short8 bf = *(const short8*)(kT + ((size_t)b * NTOK + m0 + j * 16 + lo) * NHID + 8 * lg);
    f32x4 z = {0.f, 0.f, 0.f, 0.f};
    acc[j] = __builtin_amdgcn_mfma_f32_16x16x32_bf16(a, bf, z, 0, 0, 0);
  }
  __builtin_amdgcn_s_setprio(0);
  float pm[4];
#pragma unroll
  for (int r = 0; r < 4; ++r) {
    float m = acc[0][r];
#pragma unroll
    for (int j = 1; j < 16; ++j) m = fmaxf(m, acc[j][r]);
#pragma unroll
    for (int off = 1; off < 16; off <<= 1) m = fmaxf(m, __shfl_xor(m, off, 64));
    pm[r] = m;
  }
  if (lo == 0)
#pragma unroll
    for (int r = 0; r < 4; ++r) wmax[wave][4 * lg + r] = pm[r];
  __syncthreads();
  float mr[4];
#pragma unroll
  for (int r = 0; r < 4; ++r)
    mr[r] = fmaxf(fmaxf(wmax[0][4 * lg + r], wmax[1][4 * lg + r]),
                  fmaxf(wmax[2][4 * lg + r], wmax[3][4 * lg + r]));
  float ps[4] = {0.f, 0.f, 0.f, 0.f};
#pragma unroll
  for (int j = 0; j < 16; ++j)
#pragma unroll
    for (int r = 0; r < 4; ++r) {
      float e = __expf(acc[j][r] - mr[r]);
      acc[j][r] = e;
      ps[r] += e;
    }
#pragma unroll
  for (int r = 0; r < 4; ++r)
#pragma unroll
    for (int off = 1; off < 16; off <<= 1) ps[r] += __shfl_xor(ps[r], off, 64);
  if (lo == 0)
#pragma unroll
    for (int r = 0; r < 4; ++r) wsum[wave][4 * lg + r] = ps[r];
  __syncthreads();
  float inv[4];
#pragma unroll
  for (int r = 0; r < 4; ++r)
    inv[r] = 1.f / (wsum[0][4 * lg + r] + wsum[1][4 * lg + r] +
                    wsum[2][4 * lg + r] + wsum[3][4 * lg + r]);
#pragma unroll
  for (int j = 0; j < 16; ++j)
#pragma unroll
    for (int r = 0; r < 4; ++r)
      s_lds[(4 * lg + r) * SP + m0 + j * 16 + lo] = f2b(acc[j][r] * inv[r]);
  __syncthreads();
  if constexpr (ATTN2) {
    // coalesced nontemporal f32 write (64MB stream, never re-read -> bypass L2)
    int ml = lane * 4;
    float* abase = attnf + ((size_t)b * NTOK + n0) * NTOK + m0;
#pragma unroll
    for (int n = 0; n < 16; ++n) {
      ushort4 sv = *(const ushort4*)(s_lds + n * SP + m0 + ml);
      f32x4 o = {b2f(sv.x), b2f(sv.y), b2f(sv.z), b2f(sv.w)};
      __builtin_nontemporal_store(o, (f32x4*)(abase + (size_t)n * NTOK + ml));
    }
  }
  int cb = wave * 16;
  const ushort* vbb = vb + ((size_t)b * NC + cb + lo) * NTOK;
  f32x4 acc2 = {0.f, 0.f, 0.f, 0.f}, acc3 = {0.f, 0.f, 0.f, 0.f};
  __builtin_amdgcn_s_setprio(1);
  for (int ms = 0; ms < NTOK; ms += 64) {
    short8 af0 = *(const short8*)(s_lds + lo * SP + ms + 8 * lg);
    short8 bf0 = *(const short8*)(vbb + ms + 8 * lg);
    short8 af1 = *(const short8*)(s_lds + lo * SP + ms + 32 + 8 * lg);
    short8 bf1 = *(const short8*)(vbb + ms + 32 + 8 * lg);
    acc2 = __builtin_amdgcn_mfma_f32_16x16x32_bf16(af0, bf0, acc2, 0, 0, 0);
    acc3 = __builtin_amdgcn_mfma_f32_16x16x32_bf16(af1, bf1, acc3, 0, 0, 0);
  }
  __builtin_amdgcn_s_setprio(0);
#pragma unroll
  for (int r = 0; r < 4; ++r) acc2[r] += acc3[r];
  int c = cb + lo;
  float4 rv = *(const float4*)(resid + ((size_t)b * NC + c) * NTOK + n0 + 4 * lg);
  float rvv[4] = {rv.x, rv.y, rv.z, rv.w};
  if constexpr (ATTN2) {
    float4 o;
    o.x = scale * (rvv[0] + acc2[0]); o.y = scale * (rvv[1] + acc2[1]);
    o.z = scale * (rvv[2] + acc2[2]); o.w = scale * (rvv[3] + acc2[3]);
    *(float4*)(outf + ((size_t)b * NC + c) * NTOK + n0 + 4 * lg) = o;
  } else {
#pragma unroll
    for (int r = 0; r < 4; ++r) {
      int tok = n0 + 4 * lg + r;
      float val = scale * (rvv[r] + acc2[r]);
      outb_pad[(size_t)b * PAD_BSTRIDE + ((tok >> 5) + 2) * 2304 +
               ((tok & 31) + 2) * 64 + c] = f2b(val);
    }
  }
}

// ---- conv weight pre-pass: W_lstm[oc][ic][5][5] f32 -> chunk-major layout for
// linear global_load_lds staging:
// Wb[kk][kh][chh][chunk c=(icc*4+lg)][gate g][o 0..31][e 0..7]  (8192 elem/tile)
__global__ __launch_bounds__(256) void wpre_kernel(
    const float* __restrict__ W, ushort* __restrict__ Wb) {
  int idx = blockIdx.x * 256 + threadIdx.x;   // (oc 256, ic 128)
  int oc = idx >> 7, ic = idx & 127;
  int g = oc >> 6, chh = (oc >> 5) & 1, o = oc & 31;
  int kh = ic >> 6, ic64 = ic & 63;
  int c = ic64 >> 3;          // = icc*4 + lg
  int e = ic64 & 7;
  const float* src = W + (size_t)idx * 25;
  for (int kk = 0; kk < 25; ++kk) {
    size_t dst = ((((size_t)((kk * 2 + kh) * 2 + chh) * 8 + c) * 4 + g) * 32 + o) * 8 + e;
    Wb[dst] = f2b(src[kk]);
  }
}

// ---- FUSED conv + LSTM, 2 wg/CU, A staged via global_load_lds (no ds_writes,
// no VGPR round-trip). wg = 4 waves = 128 gate-rows (32 ch x 4 gates, chh in
// grid) x 64 px. Wave: gate-quad of a 16-ch block x 32 px.
// A tile/tap = 16 KB linear (chunk-major Wb layout -> dense, conflict-free).
// K = 50 steps (25 taps x 2 kh), A dbuf, 1 barrier/step; B window (6x36x64ic,
// one kh, pitch 76) restaged at the kh switch. LSTM fused in epilogue.
// Grid (16 pt, 2 chh, 16 b) = 512 wgs. LDS 65.6 KB -> 2 wg/CU.
#define BP 76
__global__ __launch_bounds__(256, 2) void conv_lstm_kernel(
    const ushort* __restrict__ pad,   // [b][2][36*36][64] bf16
    const ushort* __restrict__ Wb,    // chunk-major (see wpre)
    const float* __restrict__ bias, const float* __restrict__ c_in,
    float* __restrict__ c_out, float* __restrict__ h_out) {
  __shared__ ushort ldsA[2][8192];    // ping-pong A tile, 16 KB each
  __shared__ ushort ldsB[216 * BP];   // [6 rows x 36 cols][64 ic], one kh
  int t = threadIdx.x;
  int lane = t & 63, lo = lane & 15, lg = lane >> 4;
  int wid = t >> 6, cb = wid & 1, ph = wid >> 1;   // cb: 16-ch block, ph: px row
  int pt = blockIdx.x, chh = blockIdx.y, b = blockIdx.z;
  const ushort* pb = pad + (size_t)b * PAD_BSTRIDE + (size_t)(pt * 2) * 2304;

  // stage B window for kh=0 (contiguous src, pre-padded zeros)
  for (int i = t; i < 1728; i += 256) {
    int pxw = i >> 3, ch8 = (i & 7) * 8;
    uint4 v = *(const uint4*)(pb + (size_t)pxw * 64 + ch8);
    *(uint4*)(ldsB + pxw * BP + ch8) = v;
  }

  // issue A tile for step s into buffer buf (4 x glds16 per wave = 4 KB)
#define ISSUE_A(buf, sv)                                                       \
  {                                                                            \
    int _kh = (sv) >= 25;                                                      \
    int _tap = (sv) - _kh * 25;                                                \
    const ushort* _src = Wb + ((size_t)((_tap * 2 + _kh) * 2 + chh)) * 8192 +  \
                         wid * 2048 + lane * 8;                                \
    ushort* _dst = &ldsA[buf][wid * 2048];                                     \
    glds16(_src,        _dst);                                                 \
    glds16(_src + 512,  _dst + 512);                                           \
    glds16(_src + 1024, _dst + 1024);                                          \
    glds16(_src + 1536, _dst + 1536);                                          \
  }

  f32x4 acc[4][2];
#pragma unroll
  for (int i = 0; i < 4; ++i)
#pragma unroll
    for (int j = 0; j < 2; ++j) acc[i][j] = {0.f, 0.f, 0.f, 0.f};

  ISSUE_A(0, 0);
  __syncthreads();            // B + A0 ready (syncthreads drains vmcnt)

  for (int s = 0; s < 50; ++s) {
    int cur = s & 1;
    if (s < 49) ISSUE_A(cur ^ 1, s + 1);   // buffer freed at end of s-1
    int kh = (s >= 25);
    int tap = s - kh * 25;
    int ky = tap / 5, kx = tap - 5 * ky;
    int bbase = (ky * 36 + kx) * BP;
    __builtin_amdgcn_s_setprio(1);
#pragma unroll
    for (int icc = 0; icc < 2; ++icc) {
      short8 af[4], bf[2];
#pragma unroll
      for (int i = 0; i < 4; ++i)   // chunk-major: c=(icc*4+lg), gate i, o=cb*16+lo
        af[i] = *(const short8*)(&ldsA[cur][((icc * 4 + lg) * 4 + i) * 256 + (cb * 16 + lo) * 8]);
#pragma unroll
      for (int j = 0; j < 2; ++j)
        bf[j] = *(const short8*)(ldsB + bbase + (ph * 36 + j * 16 + lo) * BP + icc * 32 + 8 * lg);
#pragma unroll
      for (int i = 0; i < 4; ++i)
#pragma unroll
        for (int j = 0; j < 2; ++j)
          acc[i][j] = __builtin_amdgcn_mfma_f32_16x16x32_bf16(af[i], bf[j], acc[i][j], 0, 0, 0);
    }
    __builtin_amdgcn_s_setprio(0);
    __syncthreads();          // A[nxt] landed; reads of A[cur] done
    if (s == 24) {
      // restage B for kh=1 (reads of kh0 window all done at the barrier above)
      for (int i = t; i < 1728; i += 256) {
        int pxw = i >> 3, ch8 = (i & 7) * 8;
        uint4 v = *(const uint4*)(pb + PAD_KSTRIDE + (size_t)pxw * 64 + ch8);
        *(uint4*)(ldsB + pxw * BP + ch8) = v;
      }
      __syncthreads();
    }
  }
#undef ISSUE_A

  // LSTM epilogue: thread holds gates i/f/o/g at (ch, p)
#pragma unroll
  for (int j = 0; j < 2; ++j)
#pragma unroll
    for (int r = 0; r < 4; ++r) {
      int ch = chh * 32 + cb * 16 + lg * 4 + r;
      int p = pt * 64 + ph * 32 + j * 16 + lo;
      size_t ci = ((size_t)b * NC + ch) * NTOK + p;
      float iv = sigm(acc[0][j][r] + bias[ch]);
      float fv = sigm(acc[1][j][r] + bias[64 + ch]);
      float ov = sigm(acc[2][j][r] + bias[128 + ch]);
      float gv = tanh_fast(acc[3][j][r] + bias[192 + ch]);
      float cn = fv * c_in[ci] + iv * gv;
      c_out[ci] = cn;
      h_out[ci] = ov * tanh_fast(cn);
    }
}

extern "C" void kernel_launch(void* const* d_in, const int* in_sizes, int n_in,
                              void* d_out, int out_size, void* d_ws, size_t ws_size,
                              hipStream_t stream) {
  const float* x      = (const float*)d_in[0];
  const float* h      = (const float*)d_in[1];
  const float* c      = (const float*)d_in[2];
  const float* Wq_x   = (const float*)d_in[3];
  const float* Wk_x   = (const float*)d_in[4];
  const float* Wv_x   = (const float*)d_in[5];
  const float* Wq_h   = (const float*)d_in[6];
  const float* Wk_h   = (const float*)d_in[7];
  const float* Wv_h   = (const float*)d_in[8];
  const float* W_lstm = (const float*)d_in[9];
  const float* b_lstm = (const float*)d_in[10];

  float* out   = (float*)d_out;
  float* new_h = out;                 // [16,64,32,32]
  float* new_c = out + 1048576;       // [16,64,32,32]
  float* atten = out + 2097152;       // [16,1024,1024]

  // ws layout (ushort granularity)
  ushort* wsu = (ushort*)d_ws;
  ushort* qT  = wsu;                  //   524,288 ushort [b][n][32]
  ushort* kT  = wsu + 524288;         //   524,288
  ushort* vb  = wsu + 1048576;        // 1,048,576 [b][c][m]

  // scratch aliased into the atten output region (dead until attn2):
  ushort* Wb    = (ushort*)(atten + 8388608);   // conv weights, bytes [33.55M,35.2M)
  ushort* pad   = (ushort*)(atten + 9437184);   // padded conv input, [37.7M,43.1M)
  float*  h_mid = new_h;                        // lstm h lives in new_h slot

  dim3 blk(256);
  // zero the padded conv-input ring (interiors overwritten below)
  (void)hipMemsetAsync(pad, 0, PAD_BYTES, stream);
  // ---- attention 1 on x (fused; scores never touch HBM) ----
  qkvproj_kernel<<<dim3(16, NB), blk, 0, stream>>>(x, Wq_x, Wk_x, Wv_x, qT, kT, vb);
  attn_fused_kernel<false><<<dim3(64, NB), blk, 0, stream>>>(
      qT, kT, vb, x, nullptr, nullptr, pad /*kh0 interior*/, 1.0f);
  // ---- conv-lstm (bf16 MFMA, glds A-staging, fused LSTM epilogue) ----
  wpre_kernel<<<128, blk, 0, stream>>>(W_lstm, Wb);
  tpose_pad_kernel<<<dim3(16, NB), blk, 0, stream>>>(h, pad + PAD_KSTRIDE);
  conv_lstm_kernel<<<dim3(16, 2, NB), blk, 0, stream>>>(pad, Wb, b_lstm, c, new_c, h_mid);
  // ---- attention 2 on h_mid (atten f32 is a real output) ----
  qkvproj_kernel<<<dim3(16, NB), blk, 0, stream>>>(h_mid, Wq_h, Wk_h, Wv_h, qT, kT, vb);
  attn_fused_kernel<true><<<dim3(64, NB), blk, 0, stream>>>(
      qT, kT, vb, h_mid, atten, new_h, nullptr, 2.0f);
}

// Round 17
// 131.888 us; speedup vs baseline: 1.0902x; 1.0902x over previous
//
#include <hip/hip_runtime.h>
#include <hip/hip_bf16.h>
#include <cstddef>
#include <cstdint>

// Problem constants: B=16, CIN=COUT=64, HID=32, H=W=32, K=5, PAD=2
#define NTOK 1024      // H*W
#define NB   16        // batch
#define NC   64        // channels (CIN == COUT)
#define NHID 32        // attention hidden

// padded conv input: pad[b][kh][36*36 px][64 c] bf16
#define PAD_BSTRIDE 165888   // 2*1296*64
#define PAD_KSTRIDE 82944    // 1296*64
#define PAD_BYTES   5308416  // 16 * PAD_BSTRIDE * 2

typedef __attribute__((ext_vector_type(8))) short short8;   // 8 bf16 = 4 VGPR (MFMA A/B frag)
typedef __attribute__((ext_vector_type(4))) float f32x4;    // MFMA acc frag / native v4f

// round-to-nearest-even f32 -> bf16 (as raw ushort)
__device__ __forceinline__ ushort f2b(float f) {
  uint32_t u = __builtin_bit_cast(uint32_t, f);
  return (ushort)((u + 0x7FFFu + ((u >> 16) & 1u)) >> 16);
}
__device__ __forceinline__ float b2f(ushort u) {
  return __builtin_bit_cast(float, (uint32_t)u << 16);
}
// 8 consecutive f32 -> bf16x8 frag
__device__ __forceinline__ short8 ldw8(const float* __restrict__ p) {
  float4 f0 = *(const float4*)p, f1 = *(const float4*)(p + 4);
  short8 r;
  r[0] = (short)f2b(f0.x); r[1] = (short)f2b(f0.y);
  r[2] = (short)f2b(f0.z); r[3] = (short)f2b(f0.w);
  r[4] = (short)f2b(f1.x); r[5] = (short)f2b(f1.y);
  r[6] = (short)f2b(f1.z); r[7] = (short)f2b(f1.w);
  return r;
}
__device__ __forceinline__ float sigm(float x) { return 1.f / (1.f + __expf(-x)); }
__device__ __forceinline__ float tanh_fast(float x) {
  float e = __expf(2.f * x);
  return 1.f - 2.f / (e + 1.f);   // safe at +/-inf
}

// ---- transpose + convert h f32 [b][64c][1024n] -> padded conv-input interior
__global__ __launch_bounds__(256) void tpose_pad_kernel(
    const float* __restrict__ src, ushort* __restrict__ dst) {
  __shared__ float tile[64][65];
  int t = threadIdx.x;
  int n0 = blockIdx.x * 64, b = blockIdx.y;
  const float* s = src + (size_t)b * NC * NTOK;
#pragma unroll
  for (int r = 0; r < 4; ++r) {
    int c = r * 16 + (t >> 4);
    int nl = (t & 15) * 4;
    float4 v = *(const float4*)(s + (size_t)c * NTOK + n0 + nl);
    tile[c][nl] = v.x; tile[c][nl + 1] = v.y; tile[c][nl + 2] = v.z; tile[c][nl + 3] = v.w;
  }
  __syncthreads();
  int tok = t >> 2, c0 = (t & 3) * 16;
  __attribute__((aligned(16))) ushort tmp[16];
#pragma unroll
  for (int i = 0; i < 16; ++i) tmp[i] = f2b(tile[c0 + i][tok]);
  int gtok = n0 + tok;
  ushort* d = dst + (size_t)b * PAD_BSTRIDE +
              ((gtok >> 5) + 2) * 2304 + ((gtok & 31) + 2) * 64 + c0;
  *(uint4*)(d)     = *(const uint4*)(tmp);
  *(uint4*)(d + 8) = *(const uint4*)(tmp + 8);
}

// ---- fused transpose + q,k,v projection via MFMA (reads f32 channel-major x).
__global__ __launch_bounds__(256) void qkvproj_kernel(
    const float* __restrict__ x, const float* __restrict__ Wq,
    const float* __restrict__ Wk, const float* __restrict__ Wv,
    ushort* __restrict__ qT, ushort* __restrict__ kT, ushort* __restrict__ vb) {
  __shared__ float tile[64][65];
  __shared__ ushort xb[64][72];
  __shared__ ushort sq[64][32], sk[64][32];
  int t = threadIdx.x, wave = t >> 6, lane = t & 63;
  int lo = lane & 15, lg = lane >> 4;
  int n0 = blockIdx.x * 64, b = blockIdx.y;
  const float* s = x + (size_t)b * NC * NTOK;
#pragma unroll
  for (int r = 0; r < 4; ++r) {
    int c = r * 16 + (t >> 4);
    int nl = (t & 15) * 4;
    float4 v = *(const float4*)(s + (size_t)c * NTOK + n0 + nl);
    tile[c][nl] = v.x; tile[c][nl + 1] = v.y; tile[c][nl + 2] = v.z; tile[c][nl + 3] = v.w;
  }
  __syncthreads();
  {
    int tok = t >> 2, c0 = (t & 3) * 16;
    __attribute__((aligned(16))) ushort tmp[16];
#pragma unroll
    for (int i = 0; i < 16; ++i) tmp[i] = f2b(tile[c0 + i][tok]);
    *(uint4*)(&xb[tok][c0])     = *(const uint4*)(tmp);
    *(uint4*)(&xb[tok][c0 + 8]) = *(const uint4*)(tmp + 8);
  }
  __syncthreads();
  const ushort* xrow = &xb[wave * 16 + lo][8 * lg];
  short8 a0 = *(const short8*)(xrow);
  short8 a1 = *(const short8*)(xrow + 32);
  f32x4 aq[2], ak[2];
#pragma unroll
  for (int dg = 0; dg < 2; ++dg) {
    short8 wq0 = ldw8(Wq + (size_t)(dg * 16 + lo) * NC + 8 * lg);
    short8 wq1 = ldw8(Wq + (size_t)(dg * 16 + lo) * NC + 32 + 8 * lg);
    short8 wk0 = ldw8(Wk + (size_t)(dg * 16 + lo) * NC + 8 * lg);
    short8 wk1 = ldw8(Wk + (size_t)(dg * 16 + lo) * NC + 32 + 8 * lg);
    f32x4 z = {0.f, 0.f, 0.f, 0.f};
    aq[dg] = __builtin_amdgcn_mfma_f32_16x16x32_bf16(a0, wq0, z, 0, 0, 0);
    aq[dg] = __builtin_amdgcn_mfma_f32_16x16x32_bf16(a1, wq1, aq[dg], 0, 0, 0);
    ak[dg] = __builtin_amdgcn_mfma_f32_16x16x32_bf16(a0, wk0, z, 0, 0, 0);
    ak[dg] = __builtin_amdgcn_mfma_f32_16x16x32_bf16(a1, wk1, ak[dg], 0, 0, 0);
  }
  f32x4 av[4];
#pragma unroll
  for (int g = 0; g < 4; ++g) {
    short8 wv0 = ldw8(Wv + (size_t)(g * 16 + lo) * NC + 8 * lg);
    short8 wv1 = ldw8(Wv + (size_t)(g * 16 + lo) * NC + 32 + 8 * lg);
    f32x4 z = {0.f, 0.f, 0.f, 0.f};
    av[g] = __builtin_amdgcn_mfma_f32_16x16x32_bf16(wv0, a0, z, 0, 0, 0);
    av[g] = __builtin_amdgcn_mfma_f32_16x16x32_bf16(wv1, a1, av[g], 0, 0, 0);
  }
#pragma unroll
  for (int dg = 0; dg < 2; ++dg)
#pragma unroll
    for (int r = 0; r < 4; ++r) {
      sq[wave * 16 + 4 * lg + r][dg * 16 + lo] = f2b(aq[dg][r]);
      sk[wave * 16 + 4 * lg + r][dg * 16 + lo] = f2b(ak[dg][r]);
    }
  ushort* vbase = vb + (size_t)b * NC * NTOK + n0 + wave * 16 + lo;
#pragma unroll
  for (int g = 0; g < 4; ++g)
#pragma unroll
    for (int r = 0; r < 4; ++r)
      vbase[(size_t)(g * 16 + lg * 4 + r) * NTOK] = f2b(av[g][r]);
  __syncthreads();
  int tok = t >> 2, d0 = (t & 3) * 8;
  size_t base = ((size_t)b * NTOK + n0 + tok) * NHID + d0;
  *(short8*)(qT + base) = *(const short8*)(&sq[tok][d0]);
  *(short8*)(kT + base) = *(const short8*)(&sk[tok][d0]);
}

// ---- FUSED attention: scores (MFMA) -> softmax -> S->bf16 LDS -> coalesced
// NONTEMPORAL atten write (ATTN2) -> PV (MFMA, 2-chain) -> residual epilogue.
#define SP 1048   // S-LDS pitch (ushorts): bank stride 12 -> <=2-way
template <bool ATTN2>
__global__ __launch_bounds__(256) void attn_fused_kernel(
    const ushort* __restrict__ qT, const ushort* __restrict__ kT,
    const ushort* __restrict__ vb, const float* __restrict__ resid,
    float* __restrict__ attnf, float* __restrict__ outf,
    ushort* __restrict__ outb_pad, float scale) {
  __shared__ ushort s_lds[16 * SP];
  __shared__ float wmax[4][16], wsum[4][16];
  int t = threadIdx.x, wave = t >> 6, lane = t & 63;
  int lo = lane & 15, lg = lane >> 4;
  int n0 = blockIdx.x * 16, b = blockIdx.y;
  int m0 = wave * 256;
  short8 a = *(const short8*)(qT + ((size_t)b * NTOK + n0 + lo) * NHID + 8 * lg);
  f32x4 acc[16];
#pragma unroll
  for (int j = 0; j < 16; ++j) {
    short8 bf = *(const short8*)(kT + ((size_t)b * NTOK + m0 + j * 16 + lo) * NHID + 8 * lg);
    f32x4 z = {0.f, 0.f, 0.f, 0.f};
    acc[j] = __builtin_amdgcn_mfma_f32_16x16x32_bf16(a, bf, z, 0, 0, 0);
  }
  float pm[4];
#pragma unroll
  for (int r = 0; r < 4; ++r) {
    float m = acc[0][r];
#pragma unroll
    for (int j = 1; j < 16; ++j) m = fmaxf(m, acc[j][r]);
#pragma unroll
    for (int off = 1; off < 16; off <<= 1) m = fmaxf(m, __shfl_xor(m, off, 64));
    pm[r] = m;
  }
  if (lo == 0)
#pragma unroll
    for (int r = 0; r < 4; ++r) wmax[wave][4 * lg + r] = pm[r];
  __syncthreads();
  float mr[4];
#pragma unroll
  for (int r = 0; r < 4; ++r)
    mr[r] = fmaxf(fmaxf(wmax[0][4 * lg + r], wmax[1][4 * lg + r]),
                  fmaxf(wmax[2][4 * lg + r], wmax[3][4 * lg + r]));
  float ps[4] = {0.f, 0.f, 0.f, 0.f};
#pragma unroll
  for (int j = 0; j < 16; ++j)
#pragma unroll
    for (int r = 0; r < 4; ++r) {
      float e = __expf(acc[j][r] - mr[r]);
      acc[j][r] = e;
      ps[r] += e;
    }
#pragma unroll
  for (int r = 0; r < 4; ++r)
#pragma unroll
    for (int off = 1; off < 16; off <<= 1) ps[r] += __shfl_xor(ps[r], off, 64);
  if (lo == 0)
#pragma unroll
    for (int r = 0; r < 4; ++r) wsum[wave][4 * lg + r] = ps[r];
  __syncthreads();
  float inv[4];
#pragma unroll
  for (int r = 0; r < 4; ++r)
    inv[r] = 1.f / (wsum[0][4 * lg + r] + wsum[1][4 * lg + r] +
                    wsum[2][4 * lg + r] + wsum[3][4 * lg + r]);
#pragma unroll
  for (int j = 0; j < 16; ++j)
#pragma unroll
    for (int r = 0; r < 4; ++r)
      s_lds[(4 * lg + r) * SP + m0 + j * 16 + lo] = f2b(acc[j][r] * inv[r]);
  __syncthreads();
  if constexpr (ATTN2) {
    // coalesced nontemporal f32 write (64MB stream, never re-read -> bypass L2)
    int ml = lane * 4;
    float* abase = attnf + ((size_t)b * NTOK + n0) * NTOK + m0;
#pragma unroll
    for (int n = 0; n < 16; ++n) {
      ushort4 sv = *(const ushort4*)(s_lds + n * SP + m0 + ml);
      f32x4 o = {b2f(sv.x), b2f(sv.y), b2f(sv.z), b2f(sv.w)};
      __builtin_nontemporal_store(o, (f32x4*)(abase + (size_t)n * NTOK + ml));
    }
  }
  int cb = wave * 16;
  const ushort* vbb = vb + ((size_t)b * NC + cb + lo) * NTOK;
  f32x4 acc2 = {0.f, 0.f, 0.f, 0.f}, acc3 = {0.f, 0.f, 0.f, 0.f};
  for (int ms = 0; ms < NTOK; ms += 64) {
    short8 af0 = *(const short8*)(s_lds + lo * SP + ms + 8 * lg);
    short8 bf0 = *(const short8*)(vbb + ms + 8 * lg);
    short8 af1 = *(const short8*)(s_lds + lo * SP + ms + 32 + 8 * lg);
    short8 bf1 = *(const short8*)(vbb + ms + 32 + 8 * lg);
    acc2 = __builtin_amdgcn_mfma_f32_16x16x32_bf16(af0, bf0, acc2, 0, 0, 0);
    acc3 = __builtin_amdgcn_mfma_f32_16x16x32_bf16(af1, bf1, acc3, 0, 0, 0);
  }
#pragma unroll
  for (int r = 0; r < 4; ++r) acc2[r] += acc3[r];
  int c = cb + lo;
  float4 rv = *(const float4*)(resid + ((size_t)b * NC + c) * NTOK + n0 + 4 * lg);
  float rvv[4] = {rv.x, rv.y, rv.z, rv.w};
  if constexpr (ATTN2) {
    float4 o;
    o.x = scale * (rvv[0] + acc2[0]); o.y = scale * (rvv[1] + acc2[1]);
    o.z = scale * (rvv[2] + acc2[2]); o.w = scale * (rvv[3] + acc2[3]);
    *(float4*)(outf + ((size_t)b * NC + c) * NTOK + n0 + 4 * lg) = o;
  } else {
#pragma unroll
    for (int r = 0; r < 4; ++r) {
      int tok = n0 + 4 * lg + r;
      float val = scale * (rvv[r] + acc2[r]);
      outb_pad[(size_t)b * PAD_BSTRIDE + ((tok >> 5) + 2) * 2304 +
               ((tok & 31) + 2) * 64 + c] = f2b(val);
    }
  }
}

// ---- conv weight pre-pass: W_lstm[oc][ic][5][5] f32 -> Wb[oc][25][128] bf16
__global__ __launch_bounds__(256) void wpre_kernel(
    const float* __restrict__ W, ushort* __restrict__ Wb) {
  int idx = blockIdx.x * 256 + threadIdx.x;
  const float* src = W + (size_t)idx * 25;
#pragma unroll
  for (int kk = 0; kk < 25; ++kk)
    Wb[((size_t)(idx >> 7) * 25 + kk) * 128 + (idx & 127)] = f2b(src[kk]);
}

// ---- FUSED conv + LSTM, 2-wave wg, j=4 (0.5 ds_read/MFMA), 2 wg/CU.
// wg = 128 thr = 64 gate-rows (4 gates x 16 ch; ch-quarter chq in grid) x
// 128 px (4 rows). Wave wv owns 64 px (2 rows), j=4 -> 32 MFMA per step from
// 8 A-reads + 8 B-reads. A-dbuf LDS committed from regs, 1 barrier/step;
// B window (8 rows x 36 x 64ic, one kh) restaged at the kh switch.
// K = 50 steps (25 taps x 2 kh) x 64 ic. LSTM fused in epilogue.
// Grid (8 pt, 4 chq, 16 b) = 512 wgs. LDS 61.8 KB -> 2 wg/CU.
#define AP 76
#define BP 76
__global__ __launch_bounds__(128) void conv_lstm_kernel(
    const ushort* __restrict__ pad,   // [b][2][36*36][64] bf16
    const ushort* __restrict__ Wb,    // [256 oc][25 kk][128 ic] bf16
    const float* __restrict__ bias, const float* __restrict__ c_in,
    float* __restrict__ c_out, float* __restrict__ h_out) {
  __shared__ ushort ldsA[2][64 * AP];   // ping-pong [row = gate*16+ch][64 ic]
  __shared__ ushort ldsB[288 * BP];     // [8 rows x 36 cols][64 ic], one kh
  int t = threadIdx.x;
  int lane = t & 63, lo = lane & 15, lg = lane >> 4;
  int wv = t >> 6;                      // wave: px half (2 rows each)
  int pt = blockIdx.x, chq = blockIdx.y, b = blockIdx.z;
  const ushort* pb = pad + (size_t)b * PAD_BSTRIDE + (size_t)(pt * 4) * 2304;

  // stage B window for kh=0: 288 px x 64 ic (contiguous, pre-padded zeros)
  for (int i = t; i < 2304; i += 128) {
    int pxw = i >> 3, ch8 = (i & 7) * 8;
    uint4 v = *(const uint4*)(pb + (size_t)pxw * 64 + ch8);
    *(uint4*)(ldsB + pxw * BP + ch8) = v;
  }

  // per-thread A staging: 4 x 16B chunks cover 64 rows x 64 ic (8 KB).
  // chunk idx -> row r = idx>>3 (gate = r>>4, ch = chq*16 + (r&15)), e = idx&7
  const ushort *wsrc0, *wsrc1, *wsrc2, *wsrc3;
  int adst0, adst1, adst2, adst3;
  {
    int i0 = t, i1 = 128 + t, i2 = 256 + t, i3 = 384 + t;
    int r0 = i0 >> 3, r1 = i1 >> 3, r2 = i2 >> 3, r3 = i3 >> 3;
    wsrc0 = Wb + (size_t)((r0 >> 4) * 64 + chq * 16 + (r0 & 15)) * 3200 + (i0 & 7) * 8;
    wsrc1 = Wb + (size_t)((r1 >> 4) * 64 + chq * 16 + (r1 & 15)) * 3200 + (i1 & 7) * 8;
    wsrc2 = Wb + (size_t)((r2 >> 4) * 64 + chq * 16 + (r2 & 15)) * 3200 + (i2 & 7) * 8;
    wsrc3 = Wb + (size_t)((r3 >> 4) * 64 + chq * 16 + (r3 & 15)) * 3200 + (i3 & 7) * 8;
    adst0 = r0 * AP + (i0 & 7) * 8;
    adst1 = r1 * AP + (i1 & 7) * 8;
    adst2 = r2 * AP + (i2 & 7) * 8;
    adst3 = r3 * AP + (i3 & 7) * 8;
  }
  // koff(s) = tap*128 + kh*64, s = kh*25 + tap
  uint4 w0 = *(const uint4*)(wsrc0);        // step 0
  uint4 w1 = *(const uint4*)(wsrc1);
  uint4 w2 = *(const uint4*)(wsrc2);
  uint4 w3 = *(const uint4*)(wsrc3);

  f32x4 acc[4][4];
#pragma unroll
  for (int i = 0; i < 4; ++i)
#pragma unroll
    for (int j = 0; j < 4; ++j) acc[i][j] = {0.f, 0.f, 0.f, 0.f};

  __syncthreads();            // B staged
  *(uint4*)(&ldsA[0][adst0]) = w0;
  *(uint4*)(&ldsA[0][adst1]) = w1;
  *(uint4*)(&ldsA[0][adst2]) = w2;
  *(uint4*)(&ldsA[0][adst3]) = w3;
  w0 = *(const uint4*)(wsrc0 + 128);        // step 1
  w1 = *(const uint4*)(wsrc1 + 128);
  w2 = *(const uint4*)(wsrc2 + 128);
  w3 = *(const uint4*)(wsrc3 + 128);
  __syncthreads();            // A0 ready

  for (int s = 0; s < 50; ++s) {
    int cur = s & 1;
    if (s < 49) {
      int nxt = cur ^ 1;
      *(uint4*)(&ldsA[nxt][adst0]) = w0;
      *(uint4*)(&ldsA[nxt][adst1]) = w1;
      *(uint4*)(&ldsA[nxt][adst2]) = w2;
      *(uint4*)(&ldsA[nxt][adst3]) = w3;
      int s2 = (s < 48) ? s + 2 : 49;
      int koff = (s2 < 25) ? s2 * 128 : (s2 - 25) * 128 + 64;
      w0 = *(const uint4*)(wsrc0 + koff);
      w1 = *(const uint4*)(wsrc1 + koff);
      w2 = *(const uint4*)(wsrc2 + koff);
      w3 = *(const uint4*)(wsrc3 + koff);
    }
    int kh = (s >= 25);
    int tap = s - kh * 25;
    int ky = tap / 5, kx = tap - 5 * ky;
#pragma unroll
    for (int icc = 0; icc < 2; ++icc) {
      short8 af[4], bf[4];
#pragma unroll
      for (int i = 0; i < 4; ++i)   // i = gate; A row = gate*16 + lo (ch)
        af[i] = *(const short8*)(&ldsA[cur][(i * 16 + lo) * AP + icc * 32 + 8 * lg]);
#pragma unroll
      for (int j = 0; j < 4; ++j) { // px: row wv*2+(j>>1), col (j&1)*16+lo
        int off = ((wv * 2 + (j >> 1) + ky) * 36 + (j & 1) * 16 + lo + kx) * BP;
        bf[j] = *(const short8*)(ldsB + off + icc * 32 + 8 * lg);
      }
#pragma unroll
      for (int i = 0; i < 4; ++i)
#pragma unroll
        for (int j = 0; j < 4; ++j)
          acc[i][j] = __builtin_amdgcn_mfma_f32_16x16x32_bf16(
              af[i], bf[j], acc[i][j], 0, 0, 0);
    }
    __syncthreads();
    if (s == 24) {
      // restage B for kh=1 (reads of kh0 window all done at the barrier above)
      for (int i = t; i < 2304; i += 128) {
        int pxw = i >> 3, ch8 = (i & 7) * 8;
        uint4 v = *(const uint4*)(pb + PAD_KSTRIDE + (size_t)pxw * 64 + ch8);
        *(uint4*)(ldsB + pxw * BP + ch8) = v;
      }
      __syncthreads();
    }
  }

  // LSTM epilogue: thread holds gates i/f/o/g at (ch, p)
#pragma unroll
  for (int j = 0; j < 4; ++j)
#pragma unroll
    for (int r = 0; r < 4; ++r) {
      int ch = chq * 16 + lg * 4 + r;
      int p = pt * 128 + (wv * 2 + (j >> 1)) * 32 + (j & 1) * 16 + lo;
      size_t ci = ((size_t)b * NC + ch) * NTOK + p;
      float iv = sigm(acc[0][j][r] + bias[ch]);
      float fv = sigm(acc[1][j][r] + bias[64 + ch]);
      float ov = sigm(acc[2][j][r] + bias[128 + ch]);
      float gv = tanh_fast(acc[3][j][r] + bias[192 + ch]);
      float cn = fv * c_in[ci] + iv * gv;
      c_out[ci] = cn;
      h_out[ci] = ov * tanh_fast(cn);
    }
}

extern "C" void kernel_launch(void* const* d_in, const int* in_sizes, int n_in,
                              void* d_out, int out_size, void* d_ws, size_t ws_size,
                              hipStream_t stream) {
  const float* x      = (const float*)d_in[0];
  const float* h      = (const float*)d_in[1];
  const float* c      = (const float*)d_in[2];
  const float* Wq_x   = (const float*)d_in[3];
  const float* Wk_x   = (const float*)d_in[4];
  const float* Wv_x   = (const float*)d_in[5];
  const float* Wq_h   = (const float*)d_in[6];
  const float* Wk_h   = (const float*)d_in[7];
  const float* Wv_h   = (const float*)d_in[8];
  const float* W_lstm = (const float*)d_in[9];
  const float* b_lstm = (const float*)d_in[10];

  float* out   = (float*)d_out;
  float* new_h = out;                 // [16,64,32,32]
  float* new_c = out + 1048576;       // [16,64,32,32]
  float* atten = out + 2097152;       // [16,1024,1024]

  // ws layout (ushort granularity)
  ushort* wsu = (ushort*)d_ws;
  ushort* qT  = wsu;                  //   524,288 ushort [b][n][32]
  ushort* kT  = wsu + 524288;         //   524,288
  ushort* vb  = wsu + 1048576;        // 1,048,576 [b][c][m]

  // scratch aliased into the atten output region (dead until attn2):
  ushort* Wb    = (ushort*)(atten + 8388608);   // conv weights, bytes [33.55M,35.2M)
  ushort* pad   = (ushort*)(atten + 9437184);   // padded conv input, [37.7M,43.1M)
  float*  h_mid = new_h;                        // lstm h lives in new_h slot

  dim3 blk(256);
  // zero the padded conv-input ring (interiors overwritten below)
  (void)hipMemsetAsync(pad, 0, PAD_BYTES, stream);
  // ---- attention 1 on x (fused; scores never touch HBM) ----
  qkvproj_kernel<<<dim3(16, NB), blk, 0, stream>>>(x, Wq_x, Wk_x, Wv_x, qT, kT, vb);
  attn_fused_kernel<false><<<dim3(64, NB), blk, 0, stream>>>(
      qT, kT, vb, x, nullptr, nullptr, pad /*kh0 interior*/, 1.0f);
  // ---- conv-lstm (bf16 MFMA, 2-wave j=4 tiles, fused LSTM epilogue) ----
  wpre_kernel<<<128, blk, 0, stream>>>(W_lstm, Wb);
  tpose_pad_kernel<<<dim3(16, NB), blk, 0, stream>>>(h, pad + PAD_KSTRIDE);
  conv_lstm_kernel<<<dim3(8, 4, NB), 128, 0, stream>>>(pad, Wb, b_lstm, c, new_c, h_mid);
  // ---- attention 2 on h_mid (atten f32 is a real output) ----
  qkvproj_kernel<<<dim3(16, NB), blk, 0, stream>>>(h_mid, Wq_h, Wk_h, Wv_h, qT, kT, vb);
  attn_fused_kernel<true><<<dim3(64, NB), blk, 0, stream>>>(
      qT, kT, vb, h_mid, atten, new_h, nullptr, 2.0f);
}

// Round 18
// 123.543 us; speedup vs baseline: 1.1638x; 1.0675x over previous
//
#include <hip/hip_runtime.h>
#include <hip/hip_bf16.h>
#include <cstddef>
#include <cstdint>

// Problem constants: B=16, CIN=COUT=64, HID=32, H=W=32, K=5, PAD=2
#define NTOK 1024      // H*W
#define NB   16        // batch
#define NC   64        // channels (CIN == COUT)
#define NHID 32        // attention hidden

// padded conv input: pad[b][kh][36*36 px][64 c] bf16
#define PAD_BSTRIDE 165888   // 2*1296*64
#define PAD_KSTRIDE 82944    // 1296*64

typedef __attribute__((ext_vector_type(8))) short short8;   // 8 bf16 = 4 VGPR (MFMA A/B frag)
typedef __attribute__((ext_vector_type(4))) float f32x4;    // MFMA acc frag / native v4f

// round-to-nearest-even f32 -> bf16 (as raw ushort)
__device__ __forceinline__ ushort f2b(float f) {
  uint32_t u = __builtin_bit_cast(uint32_t, f);
  return (ushort)((u + 0x7FFFu + ((u >> 16) & 1u)) >> 16);
}
__device__ __forceinline__ float b2f(ushort u) {
  return __builtin_bit_cast(float, (uint32_t)u << 16);
}
// 8 consecutive f32 -> bf16x8 frag
__device__ __forceinline__ short8 ldw8(const float* __restrict__ p) {
  float4 f0 = *(const float4*)p, f1 = *(const float4*)(p + 4);
  short8 r;
  r[0] = (short)f2b(f0.x); r[1] = (short)f2b(f0.y);
  r[2] = (short)f2b(f0.z); r[3] = (short)f2b(f0.w);
  r[4] = (short)f2b(f1.x); r[5] = (short)f2b(f1.y);
  r[6] = (short)f2b(f1.z); r[7] = (short)f2b(f1.w);
  return r;
}
__device__ __forceinline__ float sigm(float x) { return 1.f / (1.f + __expf(-x)); }
__device__ __forceinline__ float tanh_fast(float x) {
  float e = __expf(2.f * x);
  return 1.f - 2.f / (e + 1.f);   // safe at +/-inf
}

// ---- PREP: fused {h transpose -> pad kh1 interior | pad ring zero | weight
// pre-pass}. Grid (18, NB): x<16 tpose blocks, x==16 ring-zero, x==17 wpre slice.
__global__ __launch_bounds__(256) void prep_kernel(
    const float* __restrict__ h, const float* __restrict__ W,
    ushort* __restrict__ pad, ushort* __restrict__ Wb) {
  __shared__ float tile[64][65];
  int bx = blockIdx.x, b = blockIdx.y, t = threadIdx.x;
  if (bx < 16) {
    // transpose + convert h f32 [b][64c][1024n] -> pad kh1 interior
    int n0 = bx * 64;
    const float* s = h + (size_t)b * NC * NTOK;
#pragma unroll
    for (int r = 0; r < 4; ++r) {
      int c = r * 16 + (t >> 4);
      int nl = (t & 15) * 4;
      float4 v = *(const float4*)(s + (size_t)c * NTOK + n0 + nl);
      tile[c][nl] = v.x; tile[c][nl + 1] = v.y; tile[c][nl + 2] = v.z; tile[c][nl + 3] = v.w;
    }
    __syncthreads();
    int tok = t >> 2, c0 = (t & 3) * 16;
    __attribute__((aligned(16))) ushort tmp[16];
#pragma unroll
    for (int i = 0; i < 16; ++i) tmp[i] = f2b(tile[c0 + i][tok]);
    int gtok = n0 + tok;
    ushort* d = pad + (size_t)b * PAD_BSTRIDE + PAD_KSTRIDE +
                ((gtok >> 5) + 2) * 2304 + ((gtok & 31) + 2) * 64 + c0;
    *(uint4*)(d)     = *(const uint4*)(tmp);
    *(uint4*)(d + 8) = *(const uint4*)(tmp + 8);
  } else if (bx == 16) {
    // zero the 272-px ring of both kh windows for batch b
    ushort* pb = pad + (size_t)b * PAD_BSTRIDE;
    for (int i = t; i < 2 * 2176; i += 256) {   // 2176 = 272 px * 8 chunks
      int kh = i >= 2176;
      int j = i - kh * 2176;
      int r = j >> 3, e = j & 7;
      int row, col;
      if (r < 144) { int r2 = r / 36; row = (r2 < 2) ? r2 : r2 + 32; col = r - r2 * 36; }
      else { int rr = r - 144; row = 2 + (rr >> 2); int cm = rr & 3; col = (cm < 2) ? cm : cm + 32; }
      *(uint4*)(pb + (size_t)kh * PAD_KSTRIDE + (size_t)(row * 36 + col) * 64 + e * 8) =
          make_uint4(0u, 0u, 0u, 0u);
    }
  } else {
    // weight pre-pass slice: oc in [b*16, b*16+16), all 128 ic
    for (int i = t; i < 2048; i += 256) {
      int oc = b * 16 + (i >> 7), ic = i & 127;
      const float* src = W + ((size_t)oc * 128 + ic) * 25;
#pragma unroll
      for (int kk = 0; kk < 25; ++kk)
        Wb[((size_t)oc * 25 + kk) * 128 + ic] = f2b(src[kk]);
    }
  }
}

// ---- fused transpose + q,k,v projection via MFMA (reads f32 channel-major x).
__global__ __launch_bounds__(256) void qkvproj_kernel(
    const float* __restrict__ x, const float* __restrict__ Wq,
    const float* __restrict__ Wk, const float* __restrict__ Wv,
    ushort* __restrict__ qT, ushort* __restrict__ kT, ushort* __restrict__ vb) {
  __shared__ float tile[64][65];
  __shared__ ushort xb[64][72];
  __shared__ ushort sq[64][32], sk[64][32];
  int t = threadIdx.x, wave = t >> 6, lane = t & 63;
  int lo = lane & 15, lg = lane >> 4;
  int n0 = blockIdx.x * 64, b = blockIdx.y;
  const float* s = x + (size_t)b * NC * NTOK;
#pragma unroll
  for (int r = 0; r < 4; ++r) {
    int c = r * 16 + (t >> 4);
    int nl = (t & 15) * 4;
    float4 v = *(const float4*)(s + (size_t)c * NTOK + n0 + nl);
    tile[c][nl] = v.x; tile[c][nl + 1] = v.y; tile[c][nl + 2] = v.z; tile[c][nl + 3] = v.w;
  }
  __syncthreads();
  {
    int tok = t >> 2, c0 = (t & 3) * 16;
    __attribute__((aligned(16))) ushort tmp[16];
#pragma unroll
    for (int i = 0; i < 16; ++i) tmp[i] = f2b(tile[c0 + i][tok]);
    *(uint4*)(&xb[tok][c0])     = *(const uint4*)(tmp);
    *(uint4*)(&xb[tok][c0 + 8]) = *(const uint4*)(tmp + 8);
  }
  __syncthreads();
  const ushort* xrow = &xb[wave * 16 + lo][8 * lg];
  short8 a0 = *(const short8*)(xrow);
  short8 a1 = *(const short8*)(xrow + 32);
  f32x4 aq[2], ak[2];
#pragma unroll
  for (int dg = 0; dg < 2; ++dg) {
    short8 wq0 = ldw8(Wq + (size_t)(dg * 16 + lo) * NC + 8 * lg);
    short8 wq1 = ldw8(Wq + (size_t)(dg * 16 + lo) * NC + 32 + 8 * lg);
    short8 wk0 = ldw8(Wk + (size_t)(dg * 16 + lo) * NC + 8 * lg);
    short8 wk1 = ldw8(Wk + (size_t)(dg * 16 + lo) * NC + 32 + 8 * lg);
    f32x4 z = {0.f, 0.f, 0.f, 0.f};
    aq[dg] = __builtin_amdgcn_mfma_f32_16x16x32_bf16(a0, wq0, z, 0, 0, 0);
    aq[dg] = __builtin_amdgcn_mfma_f32_16x16x32_bf16(a1, wq1, aq[dg], 0, 0, 0);
    ak[dg] = __builtin_amdgcn_mfma_f32_16x16x32_bf16(a0, wk0, z, 0, 0, 0);
    ak[dg] = __builtin_amdgcn_mfma_f32_16x16x32_bf16(a1, wk1, ak[dg], 0, 0, 0);
  }
  f32x4 av[4];
#pragma unroll
  for (int g = 0; g < 4; ++g) {
    short8 wv0 = ldw8(Wv + (size_t)(g * 16 + lo) * NC + 8 * lg);
    short8 wv1 = ldw8(Wv + (size_t)(g * 16 + lo) * NC + 32 + 8 * lg);
    f32x4 z = {0.f, 0.f, 0.f, 0.f};
    av[g] = __builtin_amdgcn_mfma_f32_16x16x32_bf16(wv0, a0, z, 0, 0, 0);
    av[g] = __builtin_amdgcn_mfma_f32_16x16x32_bf16(wv1, a1, av[g], 0, 0, 0);
  }
#pragma unroll
  for (int dg = 0; dg < 2; ++dg)
#pragma unroll
    for (int r = 0; r < 4; ++r) {
      sq[wave * 16 + 4 * lg + r][dg * 16 + lo] = f2b(aq[dg][r]);
      sk[wave * 16 + 4 * lg + r][dg * 16 + lo] = f2b(ak[dg][r]);
    }
  ushort* vbase = vb + (size_t)b * NC * NTOK + n0 + wave * 16 + lo;
#pragma unroll
  for (int g = 0; g < 4; ++g)
#pragma unroll
    for (int r = 0; r < 4; ++r)
      vbase[(size_t)(g * 16 + lg * 4 + r) * NTOK] = f2b(av[g][r]);
  __syncthreads();
  int tok = t >> 2, d0 = (t & 3) * 8;
  size_t base = ((size_t)b * NTOK + n0 + tok) * NHID + d0;
  *(short8*)(qT + base) = *(const short8*)(&sq[tok][d0]);
  *(short8*)(kT + base) = *(const short8*)(&sk[tok][d0]);
}

// ---- FUSED attention: scores (MFMA) -> softmax -> S->bf16 LDS -> coalesced
// NONTEMPORAL atten write (ATTN2) -> PV (MFMA, 2-chain) -> residual epilogue.
#define SP 1048   // S-LDS pitch (ushorts): bank stride 12 -> <=2-way
template <bool ATTN2>
__global__ __launch_bounds__(256) void attn_fused_kernel(
    const ushort* __restrict__ qT, const ushort* __restrict__ kT,
    const ushort* __restrict__ vb, const float* __restrict__ resid,
    float* __restrict__ attnf, float* __restrict__ outf,
    ushort* __restrict__ outb_pad, float scale) {
  __shared__ ushort s_lds[16 * SP];
  __shared__ float wmax[4][16], wsum[4][16];
  int t = threadIdx.x, wave = t >> 6, lane = t & 63;
  int lo = lane & 15, lg = lane >> 4;
  int n0 = blockIdx.x * 16, b = blockIdx.y;
  int m0 = wave * 256;
  short8 a = *(const short8*)(qT + ((size_t)b * NTOK + n0 + lo) * NHID + 8 * lg);
  f32x4 acc[16];
#pragma unroll
  for (int j = 0; j < 16; ++j) {
    short8 bf = *(const short8*)(kT + ((size_t)b * NTOK + m0 + j * 16 + lo) * NHID + 8 * lg);
    f32x4 z = {0.f, 0.f, 0.f, 0.f};
    acc[j] = __builtin_amdgcn_mfma_f32_16x16x32_bf16(a, bf, z, 0, 0, 0);
  }
  float pm[4];
#pragma unroll
  for (int r = 0; r < 4; ++r) {
    float m = acc[0][r];
#pragma unroll
    for (int j = 1; j < 16; ++j) m = fmaxf(m, acc[j][r]);
#pragma unroll
    for (int off = 1; off < 16; off <<= 1) m = fmaxf(m, __shfl_xor(m, off, 64));
    pm[r] = m;
  }
  if (lo == 0)
#pragma unroll
    for (int r = 0; r < 4; ++r) wmax[wave][4 * lg + r] = pm[r];
  __syncthreads();
  float mr[4];
#pragma unroll
  for (int r = 0; r < 4; ++r)
    mr[r] = fmaxf(fmaxf(wmax[0][4 * lg + r], wmax[1][4 * lg + r]),
                  fmaxf(wmax[2][4 * lg + r], wmax[3][4 * lg + r]));
  float ps[4] = {0.f, 0.f, 0.f, 0.f};
#pragma unroll
  for (int j = 0; j < 16; ++j)
#pragma unroll
    for (int r = 0; r < 4; ++r) {
      float e = __expf(acc[j][r] - mr[r]);
      acc[j][r] = e;
      ps[r] += e;
    }
#pragma unroll
  for (int r = 0; r < 4; ++r)
#pragma unroll
    for (int off = 1; off < 16; off <<= 1) ps[r] += __shfl_xor(ps[r], off, 64);
  if (lo == 0)
#pragma unroll
    for (int r = 0; r < 4; ++r) wsum[wave][4 * lg + r] = ps[r];
  __syncthreads();
  float inv[4];
#pragma unroll
  for (int r = 0; r < 4; ++r)
    inv[r] = 1.f / (wsum[0][4 * lg + r] + wsum[1][4 * lg + r] +
                    wsum[2][4 * lg + r] + wsum[3][4 * lg + r]);
#pragma unroll
  for (int j = 0; j < 16; ++j)
#pragma unroll
    for (int r = 0; r < 4; ++r)
      s_lds[(4 * lg + r) * SP + m0 + j * 16 + lo] = f2b(acc[j][r] * inv[r]);
  __syncthreads();
  if constexpr (ATTN2) {
    // coalesced nontemporal f32 write (64MB stream, never re-read -> bypass L2)
    int ml = lane * 4;
    float* abase = attnf + ((size_t)b * NTOK + n0) * NTOK + m0;
#pragma unroll
    for (int n = 0; n < 16; ++n) {
      ushort4 sv = *(const ushort4*)(s_lds + n * SP + m0 + ml);
      f32x4 o = {b2f(sv.x), b2f(sv.y), b2f(sv.z), b2f(sv.w)};
      __builtin_nontemporal_store(o, (f32x4*)(abase + (size_t)n * NTOK + ml));
    }
  }
  int cb = wave * 16;
  const ushort* vbb = vb + ((size_t)b * NC + cb + lo) * NTOK;
  f32x4 acc2 = {0.f, 0.f, 0.f, 0.f}, acc3 = {0.f, 0.f, 0.f, 0.f};
  for (int ms = 0; ms < NTOK; ms += 64) {
    short8 af0 = *(const short8*)(s_lds + lo * SP + ms + 8 * lg);
    short8 bf0 = *(const short8*)(vbb + ms + 8 * lg);
    short8 af1 = *(const short8*)(s_lds + lo * SP + ms + 32 + 8 * lg);
    short8 bf1 = *(const short8*)(vbb + ms + 32 + 8 * lg);
    acc2 = __builtin_amdgcn_mfma_f32_16x16x32_bf16(af0, bf0, acc2, 0, 0, 0);
    acc3 = __builtin_amdgcn_mfma_f32_16x16x32_bf16(af1, bf1, acc3, 0, 0, 0);
  }
#pragma unroll
  for (int r = 0; r < 4; ++r) acc2[r] += acc3[r];
  int c = cb + lo;
  float4 rv = *(const float4*)(resid + ((size_t)b * NC + c) * NTOK + n0 + 4 * lg);
  float rvv[4] = {rv.x, rv.y, rv.z, rv.w};
  if constexpr (ATTN2) {
    float4 o;
    o.x = scale * (rvv[0] + acc2[0]); o.y = scale * (rvv[1] + acc2[1]);
    o.z = scale * (rvv[2] + acc2[2]); o.w = scale * (rvv[3] + acc2[3]);
    *(float4*)(outf + ((size_t)b * NC + c) * NTOK + n0 + 4 * lg) = o;
  } else {
#pragma unroll
    for (int r = 0; r < 4; ++r) {
      int tok = n0 + 4 * lg + r;
      float val = scale * (rvv[r] + acc2[r]);
      outb_pad[(size_t)b * PAD_BSTRIDE + ((tok >> 5) + 2) * 2304 +
               ((tok & 31) + 2) * 64 + c] = f2b(val);
    }
  }
}

// ---- FUSED conv + LSTM, 2 wg/CU (r11 proven config, 52us). wg = 4 waves
// = 128 gate-rows (32 ch x 4 gates, chh in grid) x 64 px. Wave: gate-quad of a
// 16-ch block x 32 px -> thread holds i,f,o,g for its (channel,px).
// K = 50 steps (25 taps x 2 kh) of 128x64ic A-tiles, dbuf, 1 barrier/step;
// B window (6x36x64ic, one kh) restaged once at the kh switch.
// Grid (16 pt, 2 chh, 16 b) = 512 wgs. LDS 71.7 KB -> 2 wg/CU.
#define AP 76
#define BP 76
__global__ __launch_bounds__(256, 2) void conv_lstm_kernel(
    const ushort* __restrict__ pad,   // [b][2][36*36][64] bf16
    const ushort* __restrict__ Wb,    // [256 oc][25 kk][128 ic] bf16
    const float* __restrict__ bias, const float* __restrict__ c_in,
    float* __restrict__ c_out, float* __restrict__ h_out) {
  __shared__ ushort ldsA[2][128 * AP];  // ping-pong [gate-row][64 ic]
  __shared__ ushort ldsB[216 * BP];     // [6 rows x 36 cols][64 ic], one kh
  int t = threadIdx.x;
  int lane = t & 63, lo = lane & 15, lg = lane >> 4;
  int wid = t >> 6, cb = wid & 1, ph = wid >> 1;   // cb: 16-ch block, ph: px row
  int pt = blockIdx.x, chh = blockIdx.y, b = blockIdx.z;
  const ushort* pb = pad + (size_t)b * PAD_BSTRIDE + (size_t)(pt * 2) * 2304;

  // stage B window for kh=0 (contiguous src, pre-padded zeros)
  for (int i = t; i < 1728; i += 256) {
    int pxw = i >> 3, ch8 = (i & 7) * 8;
    uint4 v = *(const uint4*)(pb + (size_t)pxw * 64 + ch8);
    *(uint4*)(ldsB + pxw * BP + ch8) = v;
  }

  // per-thread A staging: 4 x 16B chunks cover 128 rows x 64 ic.
  // row r: gate = r>>5, oc = gate*64 + chh*32 + (r&31)
  const ushort *wsrc0, *wsrc1, *wsrc2, *wsrc3;
  int adst0, adst1, adst2, adst3;
  {
    int i0 = t, i1 = 256 + t, i2 = 512 + t, i3 = 768 + t;
    int r0 = i0 >> 3, r1 = i1 >> 3, r2 = i2 >> 3, r3 = i3 >> 3;
    wsrc0 = Wb + (size_t)((r0 >> 5) * 64 + chh * 32 + (r0 & 31)) * 3200 + (i0 & 7) * 8;
    wsrc1 = Wb + (size_t)((r1 >> 5) * 64 + chh * 32 + (r1 & 31)) * 3200 + (i1 & 7) * 8;
    wsrc2 = Wb + (size_t)((r2 >> 5) * 64 + chh * 32 + (r2 & 31)) * 3200 + (i2 & 7) * 8;
    wsrc3 = Wb + (size_t)((r3 >> 5) * 64 + chh * 32 + (r3 & 31)) * 3200 + (i3 & 7) * 8;
    adst0 = r0 * AP + (i0 & 7) * 8;
    adst1 = r1 * AP + (i1 & 7) * 8;
    adst2 = r2 * AP + (i2 & 7) * 8;
    adst3 = r3 * AP + (i3 & 7) * 8;
  }
  // koff(s) = tap*128 + kh*64, s = kh*25 + tap
  uint4 w0 = *(const uint4*)(wsrc0);        // step 0
  uint4 w1 = *(const uint4*)(wsrc1);
  uint4 w2 = *(const uint4*)(wsrc2);
  uint4 w3 = *(const uint4*)(wsrc3);

  f32x4 acc[4][2];
#pragma unroll
  for (int i = 0; i < 4; ++i)
#pragma unroll
    for (int j = 0; j < 2; ++j) acc[i][j] = {0.f, 0.f, 0.f, 0.f};

  __syncthreads();            // B staged
  *(uint4*)(&ldsA[0][adst0]) = w0;
  *(uint4*)(&ldsA[0][adst1]) = w1;
  *(uint4*)(&ldsA[0][adst2]) = w2;
  *(uint4*)(&ldsA[0][adst3]) = w3;
  w0 = *(const uint4*)(wsrc0 + 128);        // step 1
  w1 = *(const uint4*)(wsrc1 + 128);
  w2 = *(const uint4*)(wsrc2 + 128);
  w3 = *(const uint4*)(wsrc3 + 128);
  __syncthreads();            // A0 ready

  for (int s = 0; s < 50; ++s) {
    int cur = s & 1;
    if (s < 49) {
      int nxt = cur ^ 1;
      *(uint4*)(&ldsA[nxt][adst0]) = w0;
      *(uint4*)(&ldsA[nxt][adst1]) = w1;
      *(uint4*)(&ldsA[nxt][adst2]) = w2;
      *(uint4*)(&ldsA[nxt][adst3]) = w3;
      int s2 = (s < 48) ? s + 2 : 49;
      int koff = (s2 < 25) ? s2 * 128 : (s2 - 25) * 128 + 64;
      w0 = *(const uint4*)(wsrc0 + koff);
      w1 = *(const uint4*)(wsrc1 + koff);
      w2 = *(const uint4*)(wsrc2 + koff);
      w3 = *(const uint4*)(wsrc3 + koff);
    }
    int kh = (s >= 25);
    int tap = s - kh * 25;
    int ky = tap / 5, kx = tap - 5 * ky;
    int bbase = (ky * 36 + kx) * BP;
#pragma unroll
    for (int icc = 0; icc < 2; ++icc) {
      short8 af[4], bf[2];
#pragma unroll
      for (int i = 0; i < 4; ++i)   // i = gate; A row = gate*32 + cb*16 + lo
        af[i] = *(const short8*)(&ldsA[cur][(i * 32 + cb * 16 + lo) * AP + icc * 32 + 8 * lg]);
#pragma unroll
      for (int j = 0; j < 2; ++j)
        bf[j] = *(const short8*)(ldsB + bbase + (ph * 36 + j * 16 + lo) * BP + icc * 32 + 8 * lg);
#pragma unroll
      for (int i = 0; i < 4; ++i)
#pragma unroll
        for (int j = 0; j < 2; ++j)
          acc[i][j] = __builtin_amdgcn_mfma_f32_16x16x32_bf16(af[i], bf[j], acc[i][j], 0, 0, 0);
    }
    __syncthreads();
    if (s == 24) {
      // restage B for kh=1 (reads of kh0 window all done at the barrier above)
      for (int i = t; i < 1728; i += 256) {
        int pxw = i >> 3, ch8 = (i & 7) * 8;
        uint4 v = *(const uint4*)(pb + PAD_KSTRIDE + (size_t)pxw * 64 + ch8);
        *(uint4*)(ldsB + pxw * BP + ch8) = v;
      }
      __syncthreads();
    }
  }

  // LSTM epilogue: thread holds gates i/f/o/g at (ch, p)
#pragma unroll
  for (int j = 0; j < 2; ++j)
#pragma unroll
    for (int r = 0; r < 4; ++r) {
      int ch = chh * 32 + cb * 16 + lg * 4 + r;
      int p = pt * 64 + ph * 32 + j * 16 + lo;
      size_t ci = ((size_t)b * NC + ch) * NTOK + p;
      float iv = sigm(acc[0][j][r] + bias[ch]);
      float fv = sigm(acc[1][j][r] + bias[64 + ch]);
      float ov = sigm(acc[2][j][r] + bias[128 + ch]);
      float gv = tanh_fast(acc[3][j][r] + bias[192 + ch]);
      float cn = fv * c_in[ci] + iv * gv;
      c_out[ci] = cn;
      h_out[ci] = ov * tanh_fast(cn);
    }
}

extern "C" void kernel_launch(void* const* d_in, const int* in_sizes, int n_in,
                              void* d_out, int out_size, void* d_ws, size_t ws_size,
                              hipStream_t stream) {
  const float* x      = (const float*)d_in[0];
  const float* h      = (const float*)d_in[1];
  const float* c      = (const float*)d_in[2];
  const float* Wq_x   = (const float*)d_in[3];
  const float* Wk_x   = (const float*)d_in[4];
  const float* Wv_x   = (const float*)d_in[5];
  const float* Wq_h   = (const float*)d_in[6];
  const float* Wk_h   = (const float*)d_in[7];
  const float* Wv_h   = (const float*)d_in[8];
  const float* W_lstm = (const float*)d_in[9];
  const float* b_lstm = (const float*)d_in[10];

  float* out   = (float*)d_out;
  float* new_h = out;                 // [16,64,32,32]
  float* new_c = out + 1048576;       // [16,64,32,32]
  float* atten = out + 2097152;       // [16,1024,1024]

  // ws layout (ushort granularity)
  ushort* wsu = (ushort*)d_ws;
  ushort* qT  = wsu;                  //   524,288 ushort [b][n][32]
  ushort* kT  = wsu + 524288;         //   524,288
  ushort* vb  = wsu + 1048576;        // 1,048,576 [b][c][m]

  // scratch aliased into the atten output region (dead until attn2):
  ushort* Wb    = (ushort*)(atten + 8388608);   // conv weights, bytes [33.55M,35.2M)
  ushort* pad   = (ushort*)(atten + 9437184);   // padded conv input, [37.7M,43.1M)
  float*  h_mid = new_h;                        // lstm h lives in new_h slot

  dim3 blk(256);
  // ---- prep (independent of attn1): h tpose + pad ring zero + weight prepass
  prep_kernel<<<dim3(18, NB), blk, 0, stream>>>(h, W_lstm, pad, Wb);
  // ---- attention 1 on x (fused; scores never touch HBM) ----
  qkvproj_kernel<<<dim3(16, NB), blk, 0, stream>>>(x, Wq_x, Wk_x, Wv_x, qT, kT, vb);
  attn_fused_kernel<false><<<dim3(64, NB), blk, 0, stream>>>(
      qT, kT, vb, x, nullptr, nullptr, pad /*kh0 interior*/, 1.0f);
  // ---- conv-lstm (bf16 MFMA, r11 proven config, fused LSTM epilogue) ----
  conv_lstm_kernel<<<dim3(16, 2, NB), blk, 0, stream>>>(pad, Wb, b_lstm, c, new_c, h_mid);
  // ---- attention 2 on h_mid (atten f32 is a real output) ----
  qkvproj_kernel<<<dim3(16, NB), blk, 0, stream>>>(h_mid, Wq_h, Wk_h, Wv_h, qT, kT, vb);
  attn_fused_kernel<true><<<dim3(64, NB), blk, 0, stream>>>(
      qT, kT, vb, h_mid, atten, new_h, nullptr, 2.0f);
}